// Round 1
// baseline (362.677 us; speedup 1.0000x reference)
//
#include <hip/hip_runtime.h>

typedef float f32x4 __attribute__((ext_vector_type(4)));
typedef short bf16x8 __attribute__((ext_vector_type(8)));
typedef unsigned short u16;

#define S_LEN 4096
#define DMODEL 1024
#define NH 16
#define DK 64
#define LDK 72  // 64 + 8 pad: row stride 144B = 16B-aligned, 4-bank step -> 2-way (free)

static __device__ __forceinline__ u16 f2bf(float x) {
  union { float f; unsigned u; } v; v.f = x;
  unsigned r = v.u + 0x7fffu + ((v.u >> 16) & 1u);  // RNE
  return (u16)(r >> 16);
}

// ---------------------------------------------------------------------------
// W (K,N) f32 -> Wt (N,K) bf16
// ---------------------------------------------------------------------------
__global__ __launch_bounds__(256) void wcast_t(const float* __restrict__ W,
                                               u16* __restrict__ Wt) {
  __shared__ float t[32][33];
  const int x = threadIdx.x, y = threadIdx.y;
  const int n0 = blockIdx.x * 32, k0 = blockIdx.y * 32;
#pragma unroll
  for (int i = 0; i < 4; ++i)
    t[y + 8 * i][x] = W[(size_t)(k0 + y + 8 * i) * DMODEL + n0 + x];
  __syncthreads();
#pragma unroll
  for (int i = 0; i < 4; ++i)
    Wt[(size_t)(n0 + y + 8 * i) * DMODEL + k0 + x] = f2bf(t[x][y + 8 * i]);
}

// ---------------------------------------------------------------------------
// v (H,S,64) bf16 -> vt (H,64,S) bf16
// ---------------------------------------------------------------------------
__global__ __launch_bounds__(256) void vtrans(const u16* __restrict__ v,
                                              u16* __restrict__ vt) {
  __shared__ __align__(16) u16 t[64][LDK];
  const int h = blockIdx.x >> 6;
  const int s0 = (blockIdx.x & 63) * 64;
  const int tid = threadIdx.x;
#pragma unroll
  for (int i = 0; i < 2; ++i) {
    int id = tid + i * 256;
    int r = id >> 3, c = id & 7;
    *(int4*)&t[r][c * 8] =
        *(const int4*)(v + ((size_t)h * S_LEN + s0 + r) * DK + c * 8);
  }
  __syncthreads();
#pragma unroll
  for (int i = 0; i < 2; ++i) {
    int id = tid + i * 256;
    int d = id >> 3, c = id & 7;
    union { u16 u[8]; int4 q; } tmp;
#pragma unroll
    for (int j = 0; j < 8; ++j) tmp.u[j] = t[c * 8 + j][d];
    *(int4*)&vt[((size_t)h * DK + d) * S_LEN + s0 + c * 8] = tmp.q;
  }
}

// ---------------------------------------------------------------------------
// GEMM: C(M=4096, N=1024) = A(4096,1024) @ Wt^T + bias
// A: f32 (AF32=1, cast fused in staging) or bf16 (AF32=0)
// MODE 0: out bf16 head-split (H,S,64), value=(acc+bias)*scale
// MODE 1: out f32 flat (S,D)
// 128x128 tile, BK=64, 4 waves (2x2), each wave 64x64 via 4x4 16x16x32 MFMAs
// ---------------------------------------------------------------------------
template <int AF32, int MODE>
__global__ __launch_bounds__(256) void gemm128(const void* __restrict__ Ap,
                                               const u16* __restrict__ Bt,
                                               const float* __restrict__ bias,
                                               void* __restrict__ outp,
                                               float scale) {
  __shared__ __align__(16) u16 Al[128][LDK];
  __shared__ __align__(16) u16 Bl[128][LDK];
  const int tid = threadIdx.x;
  const int wid = tid >> 6, lane = tid & 63;
  const int gq = lane >> 4, c16 = lane & 15;
  const int wm = (wid >> 1) * 64, wn = (wid & 1) * 64;
  const int m0 = blockIdx.y * 128, n0 = blockIdx.x * 128;

  f32x4 acc[4][4] = {};
  const float* Af = (const float*)Ap;
  const u16* Ab = (const u16*)Ap;

  for (int kt = 0; kt < 16; ++kt) {
    const int k0 = kt * 64;
    if (AF32) {
#pragma unroll
      for (int i = 0; i < 8; ++i) {
        int id = tid + i * 256;
        int r = id >> 4, c = id & 15;
        float4 v = *(const float4*)(Af + (size_t)(m0 + r) * DMODEL + k0 + c * 4);
        u16 a0 = f2bf(v.x), a1 = f2bf(v.y), a2 = f2bf(v.z), a3 = f2bf(v.w);
        ushort4 u; u.x = a0; u.y = a1; u.z = a2; u.w = a3;
        *(ushort4*)&Al[r][c * 4] = u;
      }
    } else {
#pragma unroll
      for (int i = 0; i < 4; ++i) {
        int id = tid + i * 256;
        int r = id >> 3, c = id & 7;
        *(int4*)&Al[r][c * 8] =
            *(const int4*)(Ab + (size_t)(m0 + r) * DMODEL + k0 + c * 8);
      }
    }
#pragma unroll
    for (int i = 0; i < 4; ++i) {
      int id = tid + i * 256;
      int r = id >> 3, c = id & 7;
      *(int4*)&Bl[r][c * 8] =
          *(const int4*)(Bt + (size_t)(n0 + r) * DMODEL + k0 + c * 8);
    }
    __syncthreads();
#pragma unroll
    for (int kk = 0; kk < 2; ++kk) {
      bf16x8 a[4], b[4];
#pragma unroll
      for (int m = 0; m < 4; ++m)
        a[m] = *(const bf16x8*)&Al[wm + m * 16 + c16][kk * 32 + gq * 8];
#pragma unroll
      for (int n = 0; n < 4; ++n)
        b[n] = *(const bf16x8*)&Bl[wn + n * 16 + c16][kk * 32 + gq * 8];
#pragma unroll
      for (int m = 0; m < 4; ++m)
#pragma unroll
        for (int n = 0; n < 4; ++n)
          acc[m][n] =
              __builtin_amdgcn_mfma_f32_16x16x32_bf16(a[m], b[n], acc[m][n], 0, 0, 0);
    }
    __syncthreads();
  }

#pragma unroll
  for (int m = 0; m < 4; ++m) {
#pragma unroll
    for (int n = 0; n < 4; ++n) {
      const int row = m0 + wm + m * 16 + gq * 4;
      const int col = n0 + wn + n * 16 + c16;
      const float b = bias[col];
#pragma unroll
      for (int j = 0; j < 4; ++j) {
        float val = (acc[m][n][j] + b) * scale;
        if (MODE == 0) {
          u16* ob = (u16*)outp;
          ob[((size_t)(col >> 6) * S_LEN + row + j) * DK + (col & 63)] = f2bf(val);
        } else {
          float* of = (float*)outp;
          of[(size_t)(row + j) * DMODEL + col] = val;
        }
      }
    }
  }
}

// ---------------------------------------------------------------------------
// Flash attention: q,k (H,S,64) bf16 (q pre-scaled by 0.125), vt (H,64,S) bf16
// -> combined (S, 1024) bf16.  Block: 1 head x 64 q-rows, 4 waves x 16 rows.
// ---------------------------------------------------------------------------
__global__ __launch_bounds__(256) void attn(const u16* __restrict__ q,
                                            const u16* __restrict__ k,
                                            const u16* __restrict__ vt,
                                            u16* __restrict__ comb) {
  __shared__ __align__(16) u16 Klds[64][LDK];
  __shared__ __align__(16) u16 Vlds[64][LDK];   // rows = d, cols = key
  __shared__ __align__(16) u16 Plds[4][16][LDK];
  const int h = blockIdx.x >> 6;
  const int q0 = (blockIdx.x & 63) * 64;
  const int tid = threadIdx.x;
  const int wid = tid >> 6, lane = tid & 63;
  const int gq = lane >> 4, c16 = lane & 15;

  // Q fragments (A-operand): row = lane&15, k = 8*(lane>>4)+j (+32 for kk=1)
  const u16* qbase = q + ((size_t)h * S_LEN + q0 + wid * 16 + c16) * DK;
  const bf16x8 qa0 = *(const bf16x8*)(qbase + gq * 8);
  const bf16x8 qa1 = *(const bf16x8*)(qbase + 32 + gq * 8);

  f32x4 o[4] = {};
  float mrow[4], lrow[4];
#pragma unroll
  for (int j = 0; j < 4; ++j) { mrow[j] = -INFINITY; lrow[j] = 0.f; }

  for (int kt = 0; kt < S_LEN / 64; ++kt) {
    // stage K tile (64 keys x 64 d) and V^T tile (64 d x 64 keys)
#pragma unroll
    for (int i = 0; i < 2; ++i) {
      int id = tid + i * 256;
      int r = id >> 3, c = id & 7;
      *(int4*)&Klds[r][c * 8] =
          *(const int4*)(k + ((size_t)h * S_LEN + kt * 64 + r) * DK + c * 8);
    }
#pragma unroll
    for (int i = 0; i < 2; ++i) {
      int id = tid + i * 256;
      int r = id >> 3, c = id & 7;
      *(int4*)&Vlds[r][c * 8] =
          *(const int4*)(vt + ((size_t)h * DK + r) * S_LEN + kt * 64 + c * 8);
    }
    __syncthreads();

    // S = q @ K^T : 16 rows x 64 keys per wave
    f32x4 s[4] = {};
#pragma unroll
    for (int t = 0; t < 4; ++t)
      s[t] = __builtin_amdgcn_mfma_f32_16x16x32_bf16(
          qa0, *(const bf16x8*)&Klds[t * 16 + c16][gq * 8], s[t], 0, 0, 0);
#pragma unroll
    for (int t = 0; t < 4; ++t)
      s[t] = __builtin_amdgcn_mfma_f32_16x16x32_bf16(
          qa1, *(const bf16x8*)&Klds[t * 16 + c16][32 + gq * 8], s[t], 0, 0, 0);

    // online softmax (rows 4*gq+j live on the 16 lanes of group gq)
    float p[4][4];
    float sc[4];
#pragma unroll
    for (int j = 0; j < 4; ++j) {
      float rm = fmaxf(fmaxf(s[0][j], s[1][j]), fmaxf(s[2][j], s[3][j]));
#pragma unroll
      for (int msk = 1; msk < 16; msk <<= 1) rm = fmaxf(rm, __shfl_xor(rm, msk));
      const float mn = fmaxf(mrow[j], rm);
      sc[j] = __expf(mrow[j] - mn);
      float sum = 0.f;
#pragma unroll
      for (int t = 0; t < 4; ++t) {
        p[t][j] = __expf(s[t][j] - mn);
        sum += p[t][j];
      }
#pragma unroll
      for (int msk = 1; msk < 16; msk <<= 1) sum += __shfl_xor(sum, msk);
      lrow[j] = lrow[j] * sc[j] + sum;
      mrow[j] = mn;
    }
#pragma unroll
    for (int n = 0; n < 4; ++n)
#pragma unroll
      for (int j = 0; j < 4; ++j) o[n][j] *= sc[j];

    // P (C/D layout) -> wave-private LDS -> A-fragments
#pragma unroll
    for (int t = 0; t < 4; ++t)
#pragma unroll
      for (int j = 0; j < 4; ++j)
        Plds[wid][gq * 4 + j][t * 16 + c16] = f2bf(p[t][j]);
    asm volatile("s_waitcnt lgkmcnt(0)" ::: "memory");

#pragma unroll
    for (int kk = 0; kk < 2; ++kk) {
      const bf16x8 pa = *(const bf16x8*)&Plds[wid][c16][kk * 32 + gq * 8];
#pragma unroll
      for (int n = 0; n < 4; ++n)
        o[n] = __builtin_amdgcn_mfma_f32_16x16x32_bf16(
            pa, *(const bf16x8*)&Vlds[n * 16 + c16][kk * 32 + gq * 8], o[n], 0, 0, 0);
    }
    __syncthreads();
  }

  // epilogue: O /= l, write bf16 into (S, 1024) combined
#pragma unroll
  for (int n = 0; n < 4; ++n) {
    const int col = h * DK + n * 16 + c16;
#pragma unroll
    for (int j = 0; j < 4; ++j) {
      const int row = q0 + wid * 16 + gq * 4 + j;
      comb[(size_t)row * DMODEL + col] = f2bf(o[n][j] / lrow[j]);
    }
  }
}

// ---------------------------------------------------------------------------
extern "C" void kernel_launch(void* const* d_in, const int* in_sizes, int n_in,
                              void* d_out, int out_size, void* d_ws, size_t ws_size,
                              hipStream_t stream) {
  (void)in_sizes; (void)n_in; (void)out_size; (void)ws_size;
  const float* Q   = (const float*)d_in[0];
  const float* K   = (const float*)d_in[1];
  const float* V   = (const float*)d_in[2];
  const float* W_Q = (const float*)d_in[3];
  const float* b_Q = (const float*)d_in[4];
  const float* W_K = (const float*)d_in[5];
  const float* b_K = (const float*)d_in[6];
  const float* W_V = (const float*)d_in[7];
  const float* b_V = (const float*)d_in[8];
  const float* W_O = (const float*)d_in[9];
  const float* b_O = (const float*)d_in[10];
  float* out = (float*)d_out;

  u16* WtQ  = (u16*)d_ws;                       // 4x 1024*1024 bf16 = 8 MB
  u16* WtK  = WtQ + (size_t)DMODEL * DMODEL;
  u16* WtV  = WtK + (size_t)DMODEL * DMODEL;
  u16* WtO  = WtV + (size_t)DMODEL * DMODEL;
  u16* qp   = WtO + (size_t)DMODEL * DMODEL;    // (H,S,64) 8 MB
  u16* kp   = qp + (size_t)S_LEN * DMODEL;
  u16* vp   = kp + (size_t)S_LEN * DMODEL;
  u16* vtp  = vp + (size_t)S_LEN * DMODEL;      // (H,64,S) 8 MB
  u16* comb = vtp + (size_t)S_LEN * DMODEL;     // (S,1024) 8 MB  -> 48 MB total

  dim3 tb(32, 8);
  dim3 tg(32, 32);
  wcast_t<<<tg, tb, 0, stream>>>(W_Q, WtQ);
  wcast_t<<<tg, tb, 0, stream>>>(W_K, WtK);
  wcast_t<<<tg, tb, 0, stream>>>(W_V, WtV);
  wcast_t<<<tg, tb, 0, stream>>>(W_O, WtO);

  dim3 gg(DMODEL / 128, S_LEN / 128);
  gemm128<1, 0><<<gg, 256, 0, stream>>>(Q, WtQ, b_Q, qp, 0.125f);  // fold 1/sqrt(dk)
  gemm128<1, 0><<<gg, 256, 0, stream>>>(K, WtK, b_K, kp, 1.0f);
  gemm128<1, 0><<<gg, 256, 0, stream>>>(V, WtV, b_V, vp, 1.0f);

  vtrans<<<NH * (S_LEN / 64), 256, 0, stream>>>(vp, vtp);
  attn<<<NH * (S_LEN / 64), 256, 0, stream>>>(qp, kp, vtp, comb);

  gemm128<0, 1><<<gg, 256, 0, stream>>>(comb, WtO, b_O, out, 1.0f);
}

// Round 2
// 225.151 us; speedup vs baseline: 1.6108x; 1.6108x over previous
//
#include <hip/hip_runtime.h>

typedef float f32x4 __attribute__((ext_vector_type(4)));
typedef float f32x16 __attribute__((ext_vector_type(16)));
typedef short bf16x8 __attribute__((ext_vector_type(8)));
typedef unsigned u32x2 __attribute__((ext_vector_type(2)));
typedef unsigned short u16;

#define S_LEN 4096
#define DMODEL 1024
#define NH 16
#define DK 64
#define LDK 72  // 64 + 8 pad for the GEMM staging tiles

// 1/sqrt(64) * log2(e): softmax runs in base-2 domain
#define SCALE_Q 0.18033688f

static __device__ __forceinline__ u16 f2bf(float x) {
  union { float f; unsigned u; } v; v.f = x;
  unsigned r = v.u + 0x7fffu + ((v.u >> 16) & 1u);  // RNE
  return (u16)(r >> 16);
}

#if __has_builtin(__builtin_amdgcn_exp2f)
#define EXP2F __builtin_amdgcn_exp2f
#else
#define EXP2F exp2f
#endif

static __device__ __forceinline__ unsigned pkbf(float lo, float hi) {
  unsigned r;
  asm("v_cvt_pk_bf16_f32 %0, %1, %2" : "=v"(r) : "v"(lo), "v"(hi));
  return r;
}

static __device__ __forceinline__ void plswap(unsigned& a, unsigned& b, int hi) {
#if __has_builtin(__builtin_amdgcn_permlane32_swap)
  u32x2 r = __builtin_amdgcn_permlane32_swap(a, b, false, false);
  a = r.x; b = r.y;
  (void)hi;
#else
  unsigned ax = __shfl_xor(a, 32), bx = __shfl_xor(b, 32);
  unsigned na = hi ? bx : a;
  unsigned nb = hi ? b : ax;
  a = na; b = nb;
#endif
}

static __device__ __forceinline__ void gload16(const void* g, void* l) {
  void* gg = (void*)g;
  __builtin_amdgcn_global_load_lds(
      (__attribute__((address_space(1))) void*)gg,
      (__attribute__((address_space(3))) void*)l, 16, 0, 0);
}

// ---------------------------------------------------------------------------
// W (K,N) f32 -> Wt (N,K) bf16
// ---------------------------------------------------------------------------
__global__ __launch_bounds__(256) void wcast_t(const float* __restrict__ W,
                                               u16* __restrict__ Wt) {
  __shared__ float t[32][33];
  const int x = threadIdx.x, y = threadIdx.y;
  const int n0 = blockIdx.x * 32, k0 = blockIdx.y * 32;
#pragma unroll
  for (int i = 0; i < 4; ++i)
    t[y + 8 * i][x] = W[(size_t)(k0 + y + 8 * i) * DMODEL + n0 + x];
  __syncthreads();
#pragma unroll
  for (int i = 0; i < 4; ++i)
    Wt[(size_t)(n0 + y + 8 * i) * DMODEL + k0 + x] = f2bf(t[x][y + 8 * i]);
}

// ---------------------------------------------------------------------------
// v (H,S,64) bf16 -> vt (H,64,S) bf16
// ---------------------------------------------------------------------------
__global__ __launch_bounds__(256) void vtrans(const u16* __restrict__ v,
                                              u16* __restrict__ vt) {
  __shared__ __align__(16) u16 t[64][LDK];
  const int h = blockIdx.x >> 6;
  const int s0 = (blockIdx.x & 63) * 64;
  const int tid = threadIdx.x;
#pragma unroll
  for (int i = 0; i < 2; ++i) {
    int id = tid + i * 256;
    int r = id >> 3, c = id & 7;
    *(int4*)&t[r][c * 8] =
        *(const int4*)(v + ((size_t)h * S_LEN + s0 + r) * DK + c * 8);
  }
  __syncthreads();
#pragma unroll
  for (int i = 0; i < 2; ++i) {
    int id = tid + i * 256;
    int d = id >> 3, c = id & 7;
    union { u16 u[8]; int4 q; } tmp;
#pragma unroll
    for (int j = 0; j < 8; ++j) tmp.u[j] = t[c * 8 + j][d];
    *(int4*)&vt[((size_t)h * DK + d) * S_LEN + s0 + c * 8] = tmp.q;
  }
}

// ---------------------------------------------------------------------------
// GEMM: C(M=4096, N=1024) = A(4096,1024) @ Wt^T + bias  (unchanged from R0)
// ---------------------------------------------------------------------------
template <int AF32, int MODE>
__global__ __launch_bounds__(256) void gemm128(const void* __restrict__ Ap,
                                               const u16* __restrict__ Bt,
                                               const float* __restrict__ bias,
                                               void* __restrict__ outp,
                                               float scale) {
  __shared__ __align__(16) u16 Al[128][LDK];
  __shared__ __align__(16) u16 Bl[128][LDK];
  const int tid = threadIdx.x;
  const int wid = tid >> 6, lane = tid & 63;
  const int gq = lane >> 4, c16 = lane & 15;
  const int wm = (wid >> 1) * 64, wn = (wid & 1) * 64;
  const int m0 = blockIdx.y * 128, n0 = blockIdx.x * 128;

  f32x4 acc[4][4] = {};
  const float* Af = (const float*)Ap;
  const u16* Ab = (const u16*)Ap;

  for (int kt = 0; kt < 16; ++kt) {
    const int k0 = kt * 64;
    if (AF32) {
#pragma unroll
      for (int i = 0; i < 8; ++i) {
        int id = tid + i * 256;
        int r = id >> 4, c = id & 15;
        float4 v = *(const float4*)(Af + (size_t)(m0 + r) * DMODEL + k0 + c * 4);
        ushort4 u;
        u.x = f2bf(v.x); u.y = f2bf(v.y); u.z = f2bf(v.z); u.w = f2bf(v.w);
        *(ushort4*)&Al[r][c * 4] = u;
      }
    } else {
#pragma unroll
      for (int i = 0; i < 4; ++i) {
        int id = tid + i * 256;
        int r = id >> 3, c = id & 7;
        *(int4*)&Al[r][c * 8] =
            *(const int4*)(Ab + (size_t)(m0 + r) * DMODEL + k0 + c * 8);
      }
    }
#pragma unroll
    for (int i = 0; i < 4; ++i) {
      int id = tid + i * 256;
      int r = id >> 3, c = id & 7;
      *(int4*)&Bl[r][c * 8] =
          *(const int4*)(Bt + (size_t)(n0 + r) * DMODEL + k0 + c * 8);
    }
    __syncthreads();
#pragma unroll
    for (int kk = 0; kk < 2; ++kk) {
      bf16x8 a[4], b[4];
#pragma unroll
      for (int m = 0; m < 4; ++m)
        a[m] = *(const bf16x8*)&Al[wm + m * 16 + c16][kk * 32 + gq * 8];
#pragma unroll
      for (int n = 0; n < 4; ++n)
        b[n] = *(const bf16x8*)&Bl[wn + n * 16 + c16][kk * 32 + gq * 8];
#pragma unroll
      for (int m = 0; m < 4; ++m)
#pragma unroll
        for (int n = 0; n < 4; ++n)
          acc[m][n] =
              __builtin_amdgcn_mfma_f32_16x16x32_bf16(a[m], b[n], acc[m][n], 0, 0, 0);
    }
    __syncthreads();
  }

#pragma unroll
  for (int m = 0; m < 4; ++m) {
#pragma unroll
    for (int n = 0; n < 4; ++n) {
      const int row = m0 + wm + m * 16 + gq * 4;
      const int col = n0 + wn + n * 16 + c16;
      const float b = bias[col];
#pragma unroll
      for (int j = 0; j < 4; ++j) {
        float val = (acc[m][n][j] + b) * scale;
        if (MODE == 0) {
          u16* ob = (u16*)outp;
          ob[((size_t)(col >> 6) * S_LEN + row + j) * DK + (col & 63)] = f2bf(val);
        } else {
          float* of = (float*)outp;
          of[(size_t)(row + j) * DMODEL + col] = val;
        }
      }
    }
  }
}

// ---------------------------------------------------------------------------
// Flash attention, swapped-QK^T structure.
// q,k: (H,S,64) bf16 (q pre-scaled by 0.125*log2e), vt: (H,64,S) bf16
// -> comb (S,1024) bf16.
// Block: 4 waves x 32 q-rows (128 q-rows); grid 16 heads x 32 = 512 blocks.
// Per KV-tile (64 keys): 8 MFMA 32x32x16 QK^T (swapped), in-register base-2
// softmax (1 shfl for max, 1 for sum), cvt_pk+permlane32_swap P->bf16,
// 8 MFMA PV. K/V^T staged to LDS via global_load_lds with XOR swizzle
// (both-sides: pre-swizzled global source + swizzled ds_read).
// ---------------------------------------------------------------------------
__global__ __launch_bounds__(256) void attn2(const u16* __restrict__ q,
                                             const u16* __restrict__ k,
                                             const u16* __restrict__ vt,
                                             u16* __restrict__ comb) {
  __shared__ __align__(16) char smem[32768];  // 2 bufs x (K 8KB + V^T 8KB)
  const int bid0 = blockIdx.x;
  const int bid = (bid0 & 7) * 64 + (bid0 >> 3);  // XCD swizzle, 512%8==0
  const int h = bid >> 5;
  const int qblk = bid & 31;
  const int tid = threadIdx.x;
  const int wid = tid >> 6, lane = tid & 63;
  const int l31 = lane & 31, hi = lane >> 5;

  const char* kpb = (const char*)k + (size_t)h * S_LEN * (DK * 2);
  const char* vtb = (const char*)vt + (size_t)h * DK * (S_LEN * 2);

  // Q B-fragments: col=q=lane&31, kdim d = 16*dt + 8*hi + j
  const int q0w = qblk * 128 + wid * 32;
  const u16* qrow = q + ((size_t)h * S_LEN + q0w + l31) * DK;
  bf16x8 qf[4];
#pragma unroll
  for (int dt = 0; dt < 4; ++dt)
    qf[dt] = *(const bf16x8*)(qrow + dt * 16 + hi * 8);

  f32x16 o0 = {}, o1 = {};   // O^T[d,q]: o0 = d 0..31, o1 = d 32..63
  float mrun = -INFINITY, lsum = 0.f;

  char* const wbase = smem;  // stage dest uses wave-uniform base
  const int woff = (tid >> 6) << 10;

  auto stage = [&](int buf, int kt) {
    char* sb = wbase + buf * 16384 + woff;
    const size_t kgl = (size_t)kt * 8192;
#pragma unroll
    for (int i = 0; i < 2; ++i) {
      int lin = i * 4096 + tid * 16;
      int sw = lin ^ (((lin >> 7) & 7) << 4);
      gload16(kpb + kgl + sw, sb + i * 4096);
    }
#pragma unroll
    for (int i = 0; i < 2; ++i) {
      int lin = i * 4096 + tid * 16;
      int sw = lin ^ (((lin >> 7) & 7) << 4);
      int row = lin >> 7;        // d index 0..63
      int col = sw & 127;        // swizzled byte within 128B row
      gload16(vtb + (size_t)row * 8192 + (size_t)kt * 128 + col,
              sb + 8192 + i * 4096);
    }
  };

  int buf = 0;
  stage(0, 0);
  __syncthreads();

  const int swz = (l31 & 7) << 4;

  for (int kt = 0; kt < S_LEN / 64; ++kt) {
    if (kt < S_LEN / 64 - 1) stage(buf ^ 1, kt + 1);
    const char* kb = smem + buf * 16384;
    const char* vb = kb + 8192;

    // QK^T swapped: st[k,q], A=K (row=key), B=Q (col=q)
    f32x16 st0 = {}, st1 = {};
    __builtin_amdgcn_s_setprio(1);
#pragma unroll
    for (int dt = 0; dt < 4; ++dt) {
      const int cb = (dt * 32 + hi * 16) ^ swz;
      bf16x8 k0 = *(const bf16x8*)(kb + (l31 << 7) + cb);
      bf16x8 k1 = *(const bf16x8*)(kb + ((32 + l31) << 7) + cb);
      st0 = __builtin_amdgcn_mfma_f32_32x32x16_bf16(k0, qf[dt], st0, 0, 0, 0);
      st1 = __builtin_amdgcn_mfma_f32_32x32x16_bf16(k1, qf[dt], st1, 0, 0, 0);
    }
    __builtin_amdgcn_s_setprio(0);

    // ---- in-register base-2 online softmax (lane q = l31, half = hi) ----
    float mloc = st0[0];
#pragma unroll
    for (int i = 1; i < 16; ++i) mloc = fmaxf(mloc, st0[i]);
#pragma unroll
    for (int i = 0; i < 16; ++i) mloc = fmaxf(mloc, st1[i]);
    float rm = fmaxf(mloc, __shfl_xor(mloc, 32));

    if (!__all(rm <= mrun + 8.f)) {  // defer-max: P bounded by 2^8
      float mnew = fmaxf(mrun, rm);
      float sc = EXP2F(mrun - mnew);
      lsum *= sc;
#pragma unroll
      for (int i = 0; i < 16; ++i) { o0[i] *= sc; o1[i] *= sc; }
      mrun = mnew;
    }

    float p0[16], p1[16];
    float s0 = 0.f, s1 = 0.f;
#pragma unroll
    for (int i = 0; i < 16; ++i) { p0[i] = EXP2F(st0[i] - mrun); s0 += p0[i]; }
#pragma unroll
    for (int i = 0; i < 16; ++i) { p1[i] = EXP2F(st1[i] - mrun); s1 += p1[i]; }
    float ss = s0 + s1;
    lsum += ss + __shfl_xor(ss, 32);

    // ---- P -> bf16 B-fragments (P^T[k,q]): cvt_pk + permlane32_swap ----
    union UF { unsigned w[4]; bf16x8 v; };
    UF f[4];
    {
      unsigned a, b;
      a = pkbf(p0[0], p0[1]);   b = pkbf(p0[4], p0[5]);   plswap(a, b, hi);
      f[0].w[0] = a; f[0].w[2] = b;
      a = pkbf(p0[2], p0[3]);   b = pkbf(p0[6], p0[7]);   plswap(a, b, hi);
      f[0].w[1] = a; f[0].w[3] = b;
      a = pkbf(p0[8], p0[9]);   b = pkbf(p0[12], p0[13]); plswap(a, b, hi);
      f[1].w[0] = a; f[1].w[2] = b;
      a = pkbf(p0[10], p0[11]); b = pkbf(p0[14], p0[15]); plswap(a, b, hi);
      f[1].w[1] = a; f[1].w[3] = b;
      a = pkbf(p1[0], p1[1]);   b = pkbf(p1[4], p1[5]);   plswap(a, b, hi);
      f[2].w[0] = a; f[2].w[2] = b;
      a = pkbf(p1[2], p1[3]);   b = pkbf(p1[6], p1[7]);   plswap(a, b, hi);
      f[2].w[1] = a; f[2].w[3] = b;
      a = pkbf(p1[8], p1[9]);   b = pkbf(p1[12], p1[13]); plswap(a, b, hi);
      f[3].w[0] = a; f[3].w[2] = b;
      a = pkbf(p1[10], p1[11]); b = pkbf(p1[14], p1[15]); plswap(a, b, hi);
      f[3].w[1] = a; f[3].w[3] = b;
    }

    // ---- PV: O^T[d,q] += V^T[d,k] P^T[k,q] ----
    __builtin_amdgcn_s_setprio(1);
#pragma unroll
    for (int kt2 = 0; kt2 < 4; ++kt2) {
      const int cb = (kt2 * 32 + hi * 16) ^ swz;
      bf16x8 v0 = *(const bf16x8*)(vb + (l31 << 7) + cb);
      bf16x8 v1 = *(const bf16x8*)(vb + ((32 + l31) << 7) + cb);
      o0 = __builtin_amdgcn_mfma_f32_32x32x16_bf16(v0, f[kt2].v, o0, 0, 0, 0);
      o1 = __builtin_amdgcn_mfma_f32_32x32x16_bf16(v1, f[kt2].v, o1, 0, 0, 0);
    }
    __builtin_amdgcn_s_setprio(0);

    __syncthreads();
    buf ^= 1;
  }

  // ---- epilogue: O/l -> comb[q, h*64 + d] ----
  const float inv = 1.f / lsum;
  u16* orow = comb + (size_t)(q0w + l31) * DMODEL + h * DK;
#pragma unroll
  for (int g = 0; g < 4; ++g) {
    ushort4 u0, u1;
    u0.x = f2bf(o0[g * 4 + 0] * inv); u0.y = f2bf(o0[g * 4 + 1] * inv);
    u0.z = f2bf(o0[g * 4 + 2] * inv); u0.w = f2bf(o0[g * 4 + 3] * inv);
    *(ushort4*)(orow + 8 * g + 4 * hi) = u0;
    u1.x = f2bf(o1[g * 4 + 0] * inv); u1.y = f2bf(o1[g * 4 + 1] * inv);
    u1.z = f2bf(o1[g * 4 + 2] * inv); u1.w = f2bf(o1[g * 4 + 3] * inv);
    *(ushort4*)(orow + 32 + 8 * g + 4 * hi) = u1;
  }
}

// ---------------------------------------------------------------------------
extern "C" void kernel_launch(void* const* d_in, const int* in_sizes, int n_in,
                              void* d_out, int out_size, void* d_ws, size_t ws_size,
                              hipStream_t stream) {
  (void)in_sizes; (void)n_in; (void)out_size; (void)ws_size;
  const float* Q   = (const float*)d_in[0];
  const float* K   = (const float*)d_in[1];
  const float* V   = (const float*)d_in[2];
  const float* W_Q = (const float*)d_in[3];
  const float* b_Q = (const float*)d_in[4];
  const float* W_K = (const float*)d_in[5];
  const float* b_K = (const float*)d_in[6];
  const float* W_V = (const float*)d_in[7];
  const float* b_V = (const float*)d_in[8];
  const float* W_O = (const float*)d_in[9];
  const float* b_O = (const float*)d_in[10];
  float* out = (float*)d_out;

  u16* WtQ  = (u16*)d_ws;
  u16* WtK  = WtQ + (size_t)DMODEL * DMODEL;
  u16* WtV  = WtK + (size_t)DMODEL * DMODEL;
  u16* WtO  = WtV + (size_t)DMODEL * DMODEL;
  u16* qp   = WtO + (size_t)DMODEL * DMODEL;    // (H,S,64)
  u16* kp   = qp + (size_t)S_LEN * DMODEL;
  u16* vp   = kp + (size_t)S_LEN * DMODEL;
  u16* vtp  = vp + (size_t)S_LEN * DMODEL;      // (H,64,S)
  u16* comb = vtp + (size_t)S_LEN * DMODEL;     // (S,1024)

  dim3 tb(32, 8);
  dim3 tg(32, 32);
  wcast_t<<<tg, tb, 0, stream>>>(W_Q, WtQ);
  wcast_t<<<tg, tb, 0, stream>>>(W_K, WtK);
  wcast_t<<<tg, tb, 0, stream>>>(W_V, WtV);
  wcast_t<<<tg, tb, 0, stream>>>(W_O, WtO);

  dim3 gg(DMODEL / 128, S_LEN / 128);
  gemm128<1, 0><<<gg, 256, 0, stream>>>(Q, WtQ, b_Q, qp, SCALE_Q);
  gemm128<1, 0><<<gg, 256, 0, stream>>>(K, WtK, b_K, kp, 1.0f);
  gemm128<1, 0><<<gg, 256, 0, stream>>>(V, WtV, b_V, vp, 1.0f);

  vtrans<<<NH * (S_LEN / 64), 256, 0, stream>>>(vp, vtp);
  attn2<<<NH * (S_LEN / 64) / 2, 256, 0, stream>>>(qp, kp, vtp, comb);

  gemm128<0, 1><<<gg, 256, 0, stream>>>(comb, WtO, b_O, out, 1.0f);
}